// Round 9
// baseline (1377.484 us; speedup 1.0000x reference)
//
#include <hip/hip_runtime.h>
#include <math.h>
#include <float.h>

#define T_SEQ  2048
#define DMODEL 512
#define NHEAD  8
#define DHEAD  64
#define FDIM   2048
#define NLAYER 4
#define NB     2
#define MROWS  (NB*T_SEQ)   // 4096

typedef _Float16 f16x8 __attribute__((ext_vector_type(8)));
typedef float    f32x4 __attribute__((ext_vector_type(4)));

// async 16B global -> LDS (wave-uniform LDS base, lane x 16B dest)
__device__ __forceinline__ void async16(const _Float16* g, _Float16* l) {
    __builtin_amdgcn_global_load_lds(
        (const __attribute__((address_space(1))) unsigned int*)g,
        (__attribute__((address_space(3))) unsigned int*)l, 16, 0, 0);
}

// ---------------------------------------------------------------------------
// fp32 vector GEMM — embedding only (K=128)
// ---------------------------------------------------------------------------
template<int BN, int EPI>
__global__ __launch_bounds__(256) void gemm_k(
    const float* __restrict__ A, const float* __restrict__ W,
    const float* __restrict__ bias, const float* __restrict__ pos,
    float* __restrict__ C, int M, int N, int K)
{
    constexpr int BM = 128;
    constexpr int BK = 32;
    constexpr int MN = BN / 16;
    __shared__ float As[BK][BM + 4];
    __shared__ float Ws[BK][BN + 4];
    const int tid = threadIdx.x;
    const int n0 = blockIdx.x * BN;
    const int m0 = blockIdx.y * BM;
    const int tx = tid & 15;
    const int ty = tid >> 4;

    float acc[8][MN];
    #pragma unroll
    for (int i = 0; i < 8; ++i)
        #pragma unroll
        for (int j = 0; j < MN; ++j) acc[i][j] = 0.f;

    for (int k0 = 0; k0 < K; k0 += BK) {
        #pragma unroll
        for (int it = 0; it < 4; ++it) {
            int qq = tid + 256 * it;
            int m = qq >> 3, kq = qq & 7;
            float4 v4 = *(const float4*)(A + (size_t)(m0 + m) * K + k0 + kq * 4);
            As[kq*4+0][m] = v4.x; As[kq*4+1][m] = v4.y;
            As[kq*4+2][m] = v4.z; As[kq*4+3][m] = v4.w;
        }
        #pragma unroll
        for (int it = 0; it < BN/32; ++it) {
            int qq = tid + 256 * it;
            int n = qq >> 3, kq = qq & 7;
            float4 v4 = *(const float4*)(W + (size_t)(n0 + n) * K + k0 + kq * 4);
            Ws[kq*4+0][n] = v4.x; Ws[kq*4+1][n] = v4.y;
            Ws[kq*4+2][n] = v4.z; Ws[kq*4+3][n] = v4.w;
        }
        __syncthreads();
        for (int kk = 0; kk < BK; ++kk) {
            float a[8], b[MN];
            float4 a0 = *(const float4*)&As[kk][ty*8];
            float4 a1 = *(const float4*)&As[kk][ty*8+4];
            a[0]=a0.x; a[1]=a0.y; a[2]=a0.z; a[3]=a0.w;
            a[4]=a1.x; a[5]=a1.y; a[6]=a1.z; a[7]=a1.w;
            float4 b0 = *(const float4*)&Ws[kk][tx*4];
            b[0]=b0.x; b[1]=b0.y; b[2]=b0.z; b[3]=b0.w;
            if constexpr (MN == 8) {
                float4 b1 = *(const float4*)&Ws[kk][64 + tx*4];
                b[4]=b1.x; b[5]=b1.y; b[6]=b1.z; b[7]=b1.w;
            }
            #pragma unroll
            for (int i = 0; i < 8; ++i)
                #pragma unroll
                for (int j = 0; j < MN; ++j)
                    acc[i][j] = fmaf(a[i], b[j], acc[i][j]);
        }
        __syncthreads();
    }

    #pragma unroll
    for (int i = 0; i < 8; ++i) {
        int m = m0 + ty*8 + i;
        #pragma unroll
        for (int jb = 0; jb < MN/4; ++jb) {
            int nn = n0 + jb*64 + tx*4;
            float4 r;
            r.x = acc[i][jb*4+0] + bias[nn+0];
            r.y = acc[i][jb*4+1] + bias[nn+1];
            r.z = acc[i][jb*4+2] + bias[nn+2];
            r.w = acc[i][jb*4+3] + bias[nn+3];
            if constexpr (EPI == 1) {
                const float* pp = pos + (size_t)(m & (T_SEQ-1)) * DMODEL + nn;
                r.x += pp[0]; r.y += pp[1]; r.z += pp[2]; r.w += pp[3];
            }
            *(float4*)(C + (size_t)m * N + nn) = r;
        }
    }
}

// ---------------------------------------------------------------------------
// f16-split MFMA GEMM: C = (1/1024)·A'[M,K]·W'[N,K]^T + bias
// async global_load_lds staging (16B/lane, wave-uniform LDS base).
// BM: 128 or 64.  ASRC: 0 dual-plane A; 1 single-plane (exact spikes).
// EPI: 0 fp32; 2 spike->fp32; 3 spike->f16 plane (x16)
// LAYOUT: 0 [M,N]; 2 fused QKV (q,k f16 planes head layout; v fp32)
// ---------------------------------------------------------------------------
template<int BM, int ASRC, int EPI, int LAYOUT>
__global__ __launch_bounds__(256, 2) void mgemm_k(
    const _Float16* __restrict__ AH, const _Float16* __restrict__ AL,
    const _Float16* __restrict__ WH, const _Float16* __restrict__ WL,
    const float* __restrict__ bias,
    float* __restrict__ O0, float* __restrict__ O1, float* __restrict__ O2,
    float* __restrict__ O3, float* __restrict__ O4,
    int M, int N, int K)
{
    constexpr int MI = BM / 32;
    __shared__ _Float16 AsH[4][BM][8];
    __shared__ _Float16 AsL[4][BM][8];
    __shared__ _Float16 WsH[4][128][8];
    __shared__ _Float16 WsL[4][128][8];

    const int tid = threadIdx.x;
    const int n0 = blockIdx.x * 128;
    const int m0 = blockIdx.y * BM;
    const int wv = tid >> 6, lane = tid & 63;
    const int mw = (wv >> 1) * (BM/2), nw = (wv & 1) * 64;
    const int fr = lane & 15;
    const int kb = lane >> 4;

    f32x4 acc[MI][4];
    #pragma unroll
    for (int i = 0; i < MI; ++i)
        #pragma unroll
        for (int j = 0; j < 4; ++j) acc[i][j] = (f32x4)(0.f);

    for (int k0 = 0; k0 < K; k0 += 32) {
        // ---- async staging: chunk (kb2,row) <- src row-major 16B ----
        if constexpr (BM == 128) {
            #pragma unroll
            for (int r = 0; r < 2; ++r) {
                const int kb2 = 2*r + (wv >> 1);
                const int row = (wv & 1) * 64;          // wave-uniform
                async16(AH + (size_t)(m0 + row + lane)*K + k0 + kb2*8, &AsH[kb2][row][0]);
                if constexpr (ASRC == 0)
                    async16(AL + (size_t)(m0 + row + lane)*K + k0 + kb2*8, &AsL[kb2][row][0]);
            }
        } else {
            async16(AH + (size_t)(m0 + lane)*K + k0 + wv*8, &AsH[wv][0][0]);
            if constexpr (ASRC == 0)
                async16(AL + (size_t)(m0 + lane)*K + k0 + wv*8, &AsL[wv][0][0]);
        }
        #pragma unroll
        for (int r = 0; r < 2; ++r) {
            const int kb2 = 2*r + (wv >> 1);
            const int row = (wv & 1) * 64;
            async16(WH + (size_t)(n0 + row + lane)*K + k0 + kb2*8, &WsH[kb2][row][0]);
            async16(WL + (size_t)(n0 + row + lane)*K + k0 + kb2*8, &WsL[kb2][row][0]);
        }
        __syncthreads();    // drains vmcnt: tiles ready

        f16x8 aH[MI], aL[MI], bH[4], bL[4];
        #pragma unroll
        for (int i = 0; i < MI; ++i) {
            aH[i] = *(const f16x8*)&AsH[kb][mw + i*16 + fr][0];
            if constexpr (ASRC == 0) aL[i] = *(const f16x8*)&AsL[kb][mw + i*16 + fr][0];
        }
        #pragma unroll
        for (int j = 0; j < 4; ++j) {
            bH[j] = *(const f16x8*)&WsH[kb][nw + j*16 + fr][0];
            bL[j] = *(const f16x8*)&WsL[kb][nw + j*16 + fr][0];
        }
        #pragma unroll
        for (int i = 0; i < MI; ++i)
            #pragma unroll
            for (int j = 0; j < 4; ++j) {
                acc[i][j] = __builtin_amdgcn_mfma_f32_16x16x32_f16(aH[i], bH[j], acc[i][j], 0, 0, 0);
                acc[i][j] = __builtin_amdgcn_mfma_f32_16x16x32_f16(aH[i], bL[j], acc[i][j], 0, 0, 0);
                if constexpr (ASRC == 0)
                    acc[i][j] = __builtin_amdgcn_mfma_f32_16x16x32_f16(aL[i], bH[j], acc[i][j], 0, 0, 0);
            }
        __syncthreads();    // fragment reads done before next async writes
    }

    const int qq = lane >> 4;
    #pragma unroll
    for (int j = 0; j < 4; ++j) {
        int n = n0 + nw + j*16 + fr;
        float bv = bias[n];
        #pragma unroll
        for (int i = 0; i < MI; ++i) {
            #pragma unroll
            for (int r = 0; r < 4; ++r) {
                int m = m0 + mw + i*16 + qq*4 + r;
                float val = acc[i][j][r] * (1.f/1024.f) + bv;
                if constexpr (EPI == 2) val = val > 0.5f ? 1.f : 0.f;
                if constexpr (EPI == 3) {
                    ((_Float16*)O0)[(size_t)m * N + n] = (val > 0.5f) ? (_Float16)16.f : (_Float16)0.f;
                } else if constexpr (LAYOUT == 0) {
                    O0[(size_t)m * N + n] = val;
                } else {
                    int b_ = m >> 11, t_ = m & (T_SEQ-1);
                    if (n < 512) {
                        size_t hl = (((size_t)(b_*NHEAD + (n>>6))*T_SEQ + t_) << 6) + (n & 63);
                        float s16 = 16.f * val;
                        _Float16 hh = (_Float16)s16;
                        ((_Float16*)O0)[hl] = hh;
                        ((_Float16*)O1)[hl] = (_Float16)(s16 - (float)hh);
                    } else if (n < 1024) {
                        int nn = n - 512;
                        size_t hl = (((size_t)(b_*NHEAD + (nn>>6))*T_SEQ + t_) << 6) + (nn & 63);
                        float s16 = 16.f * val;
                        _Float16 hh = (_Float16)s16;
                        ((_Float16*)O2)[hl] = hh;
                        ((_Float16*)O3)[hl] = (_Float16)(s16 - (float)hh);
                    } else {
                        int nn = n - 1024;
                        O4[(((size_t)(b_*NHEAD + (nn>>6))*T_SEQ + t_) << 6) + (nn & 63)] = val;
                    }
                }
            }
        }
    }
}

// ---------------------------------------------------------------------------
__global__ __launch_bounds__(256) void cvtw_k(
    const float* __restrict__ w, _Float16* __restrict__ H, _Float16* __restrict__ L,
    int n, float scale)
{
    int i = blockIdx.x * 256 + threadIdx.x;
    if (i < n) {
        float s = scale * w[i];
        _Float16 h = (_Float16)s;
        H[i] = h;
        L[i] = (_Float16)(s - (float)h);
    }
}

// all of one layer's weight conversions fused (x64 split), one launch
__global__ __launch_bounds__(256) void cvtlayer_k(
    const float* __restrict__ wq, const float* __restrict__ wk, const float* __restrict__ wv,
    const float* __restrict__ bq, const float* __restrict__ bk, const float* __restrict__ bv,
    const float* __restrict__ wo, const float* __restrict__ f1w, const float* __restrict__ f2w,
    _Float16* __restrict__ WcatH, _Float16* __restrict__ WcatL, float* __restrict__ bcat,
    _Float16* __restrict__ WoH, _Float16* __restrict__ WoL,
    _Float16* __restrict__ W1H, _Float16* __restrict__ W1L,
    _Float16* __restrict__ W2H, _Float16* __restrict__ W2L)
{
    int i = blockIdx.x * 256 + threadIdx.x;
    float w;
    _Float16 *H, *L;
    int off;
    if (i < 786432) {
        int src = i >> 18, o = i & 262143;
        w = (src == 0 ? wq : (src == 1 ? wk : wv))[o];
        H = WcatH; L = WcatL; off = i;
    } else if (i < 1048576) {
        off = i - 786432;  w = wo[off];  H = WoH; L = WoL;
    } else if (i < 2097152) {
        off = i - 1048576; w = f1w[off]; H = W1H; L = W1L;
    } else if (i < 3145728) {
        off = i - 2097152; w = f2w[off]; H = W2H; L = W2L;
    } else if (i < 3145728 + 1536) {
        int j = i - 3145728;
        int src = j >> 9, o = j & 511;
        bcat[j] = (src == 0 ? bq : (src == 1 ? bk : bv))[o];
        return;
    } else return;
    float s = 64.f * w;
    _Float16 h = (_Float16)s;
    H[off] = h;
    L[off] = (_Float16)(s - (float)h);
}

// ---------------------------------------------------------------------------
// Fused sparse attention v6 — q fragments loop-invariant in REGISTERS
// (staged once via the ss scratch region), async swizzled K staging,
// LDS 49664 B -> 3 blocks/CU. MFMA QK^T, u32-key top-32 select, VALU AV.
// ---------------------------------------------------------------------------
__global__ __launch_bounds__(256) void attn_k(
    const _Float16* __restrict__ qH, const _Float16* __restrict__ qL,
    const _Float16* __restrict__ kH, const _Float16* __restrict__ kL,
    const float* __restrict__ v,
    _Float16* __restrict__ outH, _Float16* __restrict__ outL)
{
    // ksH [128*64] @0 | ksL @16384 | ss[32][132] f32 @32768 (16896) = 49664 B
    // q staging (8192 B) + wrow/irow alias the ss region
    __shared__ unsigned char lds[49664];
    _Float16* ksH = (_Float16*)(lds);
    _Float16* ksL = (_Float16*)(lds + 16384);
    float    (*ss)[132] = (float(*)[132])(lds + 32768);
    float*    wrow      = (float*)(lds + 32768);
    int*      irow      = (int*)(lds + 32768 + 4224);
    _Float16* qtH       = (_Float16*)(lds + 32768);          // temp q stage
    _Float16* qtL       = (_Float16*)(lds + 32768 + 4096);

    const int tid = threadIdx.x;
    const int bh  = blockIdx.y;
    const int t0  = blockIdx.x * 32;
    const _Float16* qHb = qH + ((size_t)bh * T_SEQ + t0) * DHEAD;
    const _Float16* qLb = qL + ((size_t)bh * T_SEQ + t0) * DHEAD;
    const _Float16* kHb = kH + (size_t)bh * T_SEQ * DHEAD;
    const _Float16* kLb = kL + (size_t)bh * T_SEQ * DHEAD;
    const float*    vb  = v  + (size_t)bh * T_SEQ * DHEAD;

    const int wv = tid >> 6, lane = tid & 63;
    const int fr = lane & 15, q4 = lane >> 4;
    const int c0w = wv * 32;
    const int srow = tid >> 3;
    const int ssub = tid & 7;

    // async stage of one K tile (swizzled: chunk ch of row cc at slot ch^(cc&7))
    auto stage = [&](int jt) {
        const int j0 = jt * 128;
        #pragma unroll
        for (int i = 0; i < 4; ++i) {
            const int r0 = wv*32 + i*8;                 // wave-uniform
            const int cc = r0 + (lane >> 3);
            const int ch = (lane & 7) ^ (cc & 7);
            const size_t goff = (size_t)(j0 + cc) * DHEAD + ch*8;
            async16(kHb + goff, ksH + r0*64);
            async16(kLb + goff, ksL + r0*64);
        }
    };

    // stage q tile into scratch (plane: [32][64] halfs)
    {
        int r = tid >> 3, c = tid & 7;
        *(f16x8*)&qtH[r*64 + c*8] = *(const f16x8*)(qHb + r*DHEAD + c*8);
        *(f16x8*)&qtL[r*64 + c*8] = *(const f16x8*)(qLb + r*DHEAD + c*8);
    }
    stage(0);
    __syncthreads();                 // q staged + ks(0) ready

    // loop-invariant q fragments -> named registers (mi x ks x plane)
    f16x8 qH00 = *(const f16x8*)&qtH[fr*64 + q4*8];
    f16x8 qH01 = *(const f16x8*)&qtH[fr*64 + 32 + q4*8];
    f16x8 qH10 = *(const f16x8*)&qtH[(16+fr)*64 + q4*8];
    f16x8 qH11 = *(const f16x8*)&qtH[(16+fr)*64 + 32 + q4*8];
    f16x8 qL00 = *(const f16x8*)&qtL[fr*64 + q4*8];
    f16x8 qL01 = *(const f16x8*)&qtL[fr*64 + 32 + q4*8];
    f16x8 qL10 = *(const f16x8*)&qtL[(16+fr)*64 + q4*8];
    f16x8 qL11 = *(const f16x8*)&qtL[(16+fr)*64 + 32 + q4*8];
    __syncthreads();                 // frag reads done before ss writes

    unsigned kreg[32];
    #pragma unroll
    for (int i = 0; i < 32; ++i) kreg[i] = 0u;

    for (int jt = 0; jt < 16; ++jt) {
        const int j0 = jt * 128;

        // QK^T: 2 m-frags x 2 n-frags x 2 k-steps x 3 split passes
        f32x4 acc[2][2];
        acc[0][0] = (f32x4)(0.f); acc[0][1] = (f32x4)(0.f);
        acc[1][0] = (f32x4)(0.f); acc[1][1] = (f32x4)(0.f);
        #pragma unroll
        for (int ks = 0; ks < 2; ++ks) {
            const int chq = ks*4 + q4;
            f16x8 aH0 = ks ? qH01 : qH00;
            f16x8 aH1 = ks ? qH11 : qH10;
            f16x8 aL0 = ks ? qL01 : qL00;
            f16x8 aL1 = ks ? qL11 : qL10;
            #pragma unroll
            for (int nj = 0; nj < 2; ++nj) {
                const int cc = c0w + nj*16 + fr;
                const int sl = cc*64 + (chq ^ (cc & 7))*8;
                f16x8 bHf = *(const f16x8*)&ksH[sl];
                f16x8 bLf = *(const f16x8*)&ksL[sl];
                acc[0][nj] = __builtin_amdgcn_mfma_f32_16x16x32_f16(aH0, bHf, acc[0][nj], 0, 0, 0);
                acc[0][nj] = __builtin_amdgcn_mfma_f32_16x16x32_f16(aH0, bLf, acc[0][nj], 0, 0, 0);
                acc[0][nj] = __builtin_amdgcn_mfma_f32_16x16x32_f16(aL0, bHf, acc[0][nj], 0, 0, 0);
                acc[1][nj] = __builtin_amdgcn_mfma_f32_16x16x32_f16(aH1, bHf, acc[1][nj], 0, 0, 0);
                acc[1][nj] = __builtin_amdgcn_mfma_f32_16x16x32_f16(aH1, bLf, acc[1][nj], 0, 0, 0);
                acc[1][nj] = __builtin_amdgcn_mfma_f32_16x16x32_f16(aL1, bHf, acc[1][nj], 0, 0, 0);
            }
        }
        // scores to LDS (C-layout: row = mi*16 + q4*4 + r, col = c0w + nj*16 + fr)
        #pragma unroll
        for (int mi = 0; mi < 2; ++mi)
            #pragma unroll
            for (int nj = 0; nj < 2; ++nj)
                #pragma unroll
                for (int r = 0; r < 4; ++r)
                    ss[mi*16 + q4*4 + r][c0w + nj*16 + fr] = acc[mi][nj][r] * (1.f/2048.f);
        __syncthreads();                 // ss visible; all ks reads done

        if (jt < 15) stage(jt + 1);      // async; hides under select

        // branch-free select: 16 candidates / thread, u32 packed keys
        float4 c4[4];
        {
            const float* ssr = &ss[srow][0] + ssub*4;
            #pragma unroll
            for (int g = 0; g < 4; ++g) c4[g] = *(const float4*)(ssr + g*32);
        }
        unsigned cand[16];
        #pragma unroll
        for (int g = 0; g < 4; ++g) {
            float vg[4] = {c4[g].x, c4[g].y, c4[g].z, c4[g].w};
            #pragma unroll
            for (int r = 0; r < 4; ++r) {
                unsigned u = __float_as_uint(vg[r]);
                u ^= (unsigned)((int)u >> 31) | 0x80000000u;
                int col = ssub*4 + g*32 + r;
                cand[g*4+r] = (u & 0xFFFFF800u) | (unsigned)(2047 - (j0 + col));
            }
        }
        #pragma unroll
        for (int k2 = 2; k2 <= 16; k2 <<= 1) {
            #pragma unroll
            for (int j2 = k2 >> 1; j2 > 0; j2 >>= 1) {
                #pragma unroll
                for (int i2 = 0; i2 < 16; ++i2) {
                    int l2 = i2 ^ j2;
                    if (l2 > i2) {
                        unsigned a = cand[i2], b = cand[l2];
                        bool sw = ((i2 & k2) == 0) ? (a < b) : (a > b);
                        cand[i2] = sw ? b : a;
                        cand[l2] = sw ? a : b;
                    }
                }
            }
        }
        #pragma unroll
        for (int j2 = 0; j2 < 16; ++j2) {
            unsigned b = cand[15 - j2];
            if (kreg[16 + j2] < b) kreg[16 + j2] = b;
        }
        #pragma unroll
        for (int st = 16; st >= 1; st >>= 1) {
            #pragma unroll
            for (int i2 = 0; i2 < 32; ++i2) {
                if ((i2 & st) == 0) {
                    unsigned lo = kreg[i2], hi = kreg[i2 | st];
                    kreg[i2]      = lo < hi ? hi : lo;
                    kreg[i2 | st] = lo < hi ? lo : hi;
                }
            }
        }
        __syncthreads();                 // ks(t+1) ready; ss reads done
    }

    // merge 8 per-sub lists (lane^1,2,4)
    #pragma unroll
    for (int s = 1; s <= 4; s <<= 1) {
        #pragma unroll
        for (int i = 0; i < 16; ++i) {
            unsigned pa = (unsigned)__shfl_xor((int)kreg[31-i], s, 64);
            unsigned pb = (unsigned)__shfl_xor((int)kreg[i],    s, 64);
            if (pa > kreg[i])    kreg[i]    = pa;
            if (pb > kreg[31-i]) kreg[31-i] = pb;
        }
        #pragma unroll
        for (int st = 16; st >= 1; st >>= 1) {
            #pragma unroll
            for (int i2 = 0; i2 < 32; ++i2) {
                if ((i2 & st) == 0) {
                    unsigned lo = kreg[i2], hi = kreg[i2 | st];
                    kreg[i2]      = lo < hi ? hi : lo;
                    kreg[i2 | st] = lo < hi ? lo : hi;
                }
            }
        }
    }

    // softmax over kept 32
    if (ssub == 0) {
        float w[32];
        #pragma unroll
        for (int i = 0; i < 32; ++i) {
            unsigned um = kreg[i] & 0xFFFFF800u;
            unsigned ub = (um & 0x80000000u) ? (um ^ 0x80000000u) : ~um;
            w[i] = __uint_as_float(ub);
        }
        float m = w[0];
        float s = 0.f;
        #pragma unroll
        for (int i = 0; i < 32; ++i) { w[i] = expf(w[i] - m); s += w[i]; }
        float inv = 1.f / s;
        #pragma unroll
        for (int i = 0; i < 32; ++i) {
            wrow[srow*33 + i] = w[i] * inv;
            irow[srow*33 + i] = 2047 - (int)(kreg[i] & 0x7FFu);
        }
    }
    __syncthreads();

    // AV: wave per row-group, lane = head dim
    const int wid = tid >> 6, lane2 = tid & 63;
    const int b = bh >> 3, h = bh & 7;
    for (int rr = wid; rr < 32; rr += 4) {
        float accv = 0.f;
        #pragma unroll
        for (int i = 0; i < 32; ++i) {
            float wgt = wrow[rr*33 + i];
            int   idx = irow[rr*33 + i];
            accv = fmaf(wgt, vb[(size_t)idx * DHEAD + lane2], accv);
        }
        size_t oi = ((size_t)(b * T_SEQ + t0 + rr)) * DMODEL + h * DHEAD + lane2;
        float s16 = 16.f * accv;
        _Float16 hh = (_Float16)s16;
        outH[oi] = hh;
        outL[oi] = (_Float16)(s16 - (float)hh);
    }
}

// ---------------------------------------------------------------------------
// LayerNorm (+residual); also emits x16 f16 hi/lo planes of the output
// ---------------------------------------------------------------------------
__global__ __launch_bounds__(256) void ln_k(
    const float* __restrict__ x, const float* __restrict__ res,
    const float* __restrict__ g, const float* __restrict__ bb,
    float* __restrict__ out, _Float16* __restrict__ oH, _Float16* __restrict__ oL)
{
    __shared__ float red[8];
    const int row = blockIdx.x;
    const int tid = threadIdx.x;
    const float* xr = x + (size_t)row * DMODEL;
    float v0 = xr[tid], v1 = xr[tid + 256];
    if (res) {
        const float* rr = res + (size_t)row * DMODEL;
        v0 += rr[tid]; v1 += rr[tid + 256];
    }
    float s = v0 + v1;
    #pragma unroll
    for (int o = 1; o < 64; o <<= 1) s += __shfl_xor(s, o);
    const int wid = tid >> 6, lane = tid & 63;
    if (lane == 0) red[wid] = s;
    __syncthreads();
    float mean = (red[0] + red[1] + red[2] + red[3]) * (1.f / DMODEL);
    float d0 = v0 - mean, d1 = v1 - mean;
    float qs = d0*d0 + d1*d1;
    #pragma unroll
    for (int o = 1; o < 64; o <<= 1) qs += __shfl_xor(qs, o);
    if (lane == 0) red[4 + wid] = qs;
    __syncthreads();
    float var = (red[4] + red[5] + red[6] + red[7]) * (1.f / DMODEL);
    float rs = rsqrtf(var + 1e-5f);
    float o0 = d0 * rs * g[tid]       + bb[tid];
    float o1 = d1 * rs * g[tid + 256] + bb[tid + 256];
    size_t base = (size_t)row * DMODEL;
    out[base + tid]       = o0;
    out[base + tid + 256] = o1;
    float s0 = 16.f * o0, s1 = 16.f * o1;
    _Float16 h0 = (_Float16)s0, h1 = (_Float16)s1;
    oH[base + tid]       = h0;
    oH[base + tid + 256] = h1;
    oL[base + tid]       = (_Float16)(s0 - (float)h0);
    oL[base + tid + 256] = (_Float16)(s1 - (float)h1);
}

// ---------------------------------------------------------------------------
__global__ __launch_bounds__(256) void pool_k(
    const float* __restrict__ h, float* __restrict__ part)
{
    const int chunk = blockIdx.x & 15;
    const int idx = (blockIdx.x >> 4) * 256 + threadIdx.x;
    const int b = idx >> 9, d = idx & 511;
    const float* p = h + ((size_t)b * T_SEQ + chunk * 128) * DMODEL + d;
    float s = 0.f;
    for (int t = 0; t < 128; ++t) s += p[(size_t)t * DMODEL];
    part[chunk * 1024 + idx] = s;
}

__global__ __launch_bounds__(256) void poolsum_k(
    const float* __restrict__ part, float* __restrict__ pooled)
{
    int idx = blockIdx.x * 256 + threadIdx.x;
    float s = 0.f;
    #pragma unroll
    for (int c = 0; c < 16; ++c) s += part[c * 1024 + idx];
    pooled[idx] = s * (1.f / T_SEQ);
}

__global__ __launch_bounds__(256) void cls_k(
    const float* __restrict__ pooled, const float* __restrict__ w,
    const float* __restrict__ bias, float* __restrict__ out)
{
    const int wid = threadIdx.x >> 6, lane = threadIdx.x & 63;
    const int oi = blockIdx.x * 4 + wid;
    const int b = oi >> 8, o = oi & 255;
    const float* pr = pooled + b * DMODEL;
    const float* wr = w + (size_t)o * DMODEL;
    float s = 0.f;
    for (int d = lane; d < DMODEL; d += 64) s = fmaf(pr[d], wr[d], s);
    #pragma unroll
    for (int off = 1; off < 64; off <<= 1) s += __shfl_xor(s, off);
    if (lane == 0) out[oi] = s + bias[o];
}

// ---------------------------------------------------------------------------
extern "C" void kernel_launch(void* const* d_in, const int* in_sizes, int n_in,
                              void* d_out, int out_size, void* d_ws, size_t ws_size,
                              hipStream_t stream)
{
    const float* x     = (const float*)d_in[0];
    const float* emb_w = (const float*)d_in[1];
    const float* emb_b = (const float*)d_in[2];
    const float* pos   = (const float*)d_in[3];
    const float* wq    = (const float*)d_in[4];
    const float* bq    = (const float*)d_in[5];
    const float* wk    = (const float*)d_in[6];
    const float* bk    = (const float*)d_in[7];
    const float* wv    = (const float*)d_in[8];
    const float* bv    = (const float*)d_in[9];
    const float* wo    = (const float*)d_in[10];
    const float* bo    = (const float*)d_in[11];
    const float* ln1g  = (const float*)d_in[12];
    const float* ln1b  = (const float*)d_in[13];
    const float* fc1w  = (const float*)d_in[14];
    const float* fc1b  = (const float*)d_in[15];
    const float* fc2w  = (const float*)d_in[16];
    const float* fc2b  = (const float*)d_in[17];
    const float* ln2g  = (const float*)d_in[18];
    const float* ln2b  = (const float*)d_in[19];
    const float* fng   = (const float*)d_in[20];
    const float* fnb   = (const float*)d_in[21];
    const float* clsw  = (const float*)d_in[22];
    const float* clsb  = (const float*)d_in[23];

    float* ws = (float*)d_ws;
    const size_t SZ  = (size_t)MROWS * DMODEL;   // 2,097,152 floats
    const size_t HP  = SZ / 2;
    float*     h     = ws;
    float*     t1    = ws + 1*SZ;
    _Float16*  hH    = (_Float16*)(ws + 2*SZ);
    _Float16*  hL    = (_Float16*)(ws + 2*SZ + HP);
    _Float16*  aoH   = (_Float16*)(ws + 3*SZ);
    _Float16*  aoL   = (_Float16*)(ws + 3*SZ + HP);
    _Float16*  qbH   = (_Float16*)(ws + 4*SZ);
    _Float16*  qbL   = (_Float16*)(ws + 4*SZ + HP);
    _Float16*  kbH   = (_Float16*)(ws + 5*SZ);
    _Float16*  kbL   = (_Float16*)(ws + 5*SZ + HP);
    float*     vbuf  = ws + 6*SZ;
    _Float16*  WcatH = (_Float16*)(ws + 7*SZ);
    _Float16*  WcatL = (_Float16*)(ws + 7*SZ + 393216);
    _Float16*  WoH   = (_Float16*)(ws + 7*SZ + 786432);
    _Float16*  WoL   = (_Float16*)(ws + 7*SZ + 917504);
    _Float16*  W1H   = (_Float16*)(ws + 7*SZ + 1048576);
    _Float16*  W1L   = (_Float16*)(ws + 7*SZ + 1572864);
    _Float16*  W2H   = (_Float16*)(ws + 7*SZ + 2097152);
    _Float16*  W2L   = (_Float16*)(ws + 7*SZ + 2621440);
    float*     bcat  = ws + 7*SZ + 3145728;
    float*     pooled= ws + 7*SZ + 3145728 + 1536;
    float*     part  = ws + 7*SZ + 3145728 + 1536 + 1024;
    _Float16*  hid   = (_Float16*)(ws + 4*SZ);   // aliases q/k planes (dead then)
    const size_t needed = (7*SZ + 3145728 + 1536 + 1024 + 16384) * sizeof(float);
    if (ws_size < needed) return;

    dim3 blk(256);

    gemm_k<64,1><<<dim3(DMODEL/64, MROWS/128), blk, 0, stream>>>(
        x, emb_w, emb_b, pos, h, MROWS, DMODEL, 128);
    cvtw_k<<<dim3((int)(SZ/256)), blk, 0, stream>>>(h, hH, hL, (int)SZ, 16.f);

    for (int l = 0; l < NLAYER; ++l) {
        const float* wq_l = wq + (size_t)l*DMODEL*DMODEL;
        const float* bq_l = bq + (size_t)l*DMODEL;
        const float* wk_l = wk + (size_t)l*DMODEL*DMODEL;
        const float* bk_l = bk + (size_t)l*DMODEL;
        const float* wv_l = wv + (size_t)l*DMODEL*DMODEL;
        const float* bv_l = bv + (size_t)l*DMODEL;
        const float* wo_l = wo + (size_t)l*DMODEL*DMODEL;
        const float* bo_l = bo + (size_t)l*DMODEL;
        const float* f1w_l = fc1w + (size_t)l*FDIM*DMODEL;
        const float* f1b_l = fc1b + (size_t)l*FDIM;
        const float* f2w_l = fc2w + (size_t)l*DMODEL*FDIM;
        const float* f2b_l = fc2b + (size_t)l*DMODEL;

        cvtlayer_k<<<dim3(12294), blk, 0, stream>>>(
            wq_l, wk_l, wv_l, bq_l, bk_l, bv_l, wo_l, f1w_l, f2w_l,
            WcatH, WcatL, bcat, WoH, WoL, W1H, W1L, W2H, W2L);

        // fused QKV (BM=64 -> 768 blocks): q,k f16 planes head layout, v fp32
        mgemm_k<64,0,0,2><<<dim3(12, 64), blk, 0, stream>>>(
            hH, hL, WcatH, WcatL, bcat,
            (float*)qbH, (float*)qbL, (float*)kbH, (float*)kbL, vbuf,
            MROWS, 1536, DMODEL);

        attn_k<<<dim3(T_SEQ/32, NB*NHEAD), blk, 0, stream>>>(
            qbH, qbL, kbH, kbL, vbuf, aoH, aoL);

        // o-proj + spike (BM=64 -> 256 blocks)
        mgemm_k<64,0,2,0><<<dim3(4, 64), blk, 0, stream>>>(
            aoH, aoL, WoH, WoL, bo_l, t1, nullptr, nullptr, nullptr, nullptr,
            MROWS, DMODEL, DMODEL);
        ln_k<<<dim3(MROWS), blk, 0, stream>>>(h, t1, ln1g + (size_t)l*DMODEL,
                                              ln1b + (size_t)l*DMODEL, h, hH, hL);

        // FFN: fc1 (BM=128, 512 blocks) spike->f16; fc2 (BM=64, 256 blocks)
        mgemm_k<128,0,3,0><<<dim3(16, 32), blk, 0, stream>>>(
            hH, hL, W1H, W1L, f1b_l, (float*)hid, nullptr, nullptr, nullptr, nullptr,
            MROWS, FDIM, DMODEL);
        mgemm_k<64,1,2,0><<<dim3(4, 64), blk, 0, stream>>>(
            hid, nullptr, W2H, W2L, f2b_l, t1, nullptr, nullptr, nullptr, nullptr,
            MROWS, DMODEL, FDIM);
        ln_k<<<dim3(MROWS), blk, 0, stream>>>(h, t1, ln2g + (size_t)l*DMODEL,
                                              ln2b + (size_t)l*DMODEL, h, hH, hL);
    }

    ln_k<<<dim3(MROWS), blk, 0, stream>>>(h, nullptr, fng, fnb, h, hH, hL);
    pool_k<<<dim3(64), blk, 0, stream>>>(h, part);
    poolsum_k<<<dim3(4), blk, 0, stream>>>(part, pooled);
    cls_k<<<dim3(128), blk, 0, stream>>>(pooled, clsw, clsb, (float*)d_out);
}